// Round 8
// baseline (364.585 us; speedup 1.0000x reference)
//
#include <hip/hip_runtime.h>
#include <hip/hip_fp16.h>

#define N_NODES 100000
#define N_EDGES 1600000
#define CH 128
#define OCH 64
#define NBUCKET 391   // ceil(100000/256) dst-buckets of 256 nodes
#define CAP 8192      // bucket capacity (mean 4092, sd ~64)
#define BIN_CHUNK 4096
#define ZROW N_NODES  // index of the guaranteed-zero h row (predication target)
#define GG 782        // ceil(100000/128) gemm blocks

typedef _Float16 half8 __attribute__((ext_vector_type(8)));
typedef float f32x4 __attribute__((ext_vector_type(4)));

__device__ __forceinline__ ushort f2h(float f) {
    _Float16 h = (_Float16)f;
    return *(ushort*)&h;
}

__device__ __forceinline__ uint pkadd(uint a, uint b) {
    __half2 r = __hadd2(*(__half2*)&a, *(__half2*)&b);
    return *(uint*)&r;
}

__device__ __forceinline__ uint4 pk4(uint4 a, uint4 b) {
    a.x = pkadd(a.x, b.x); a.y = pkadd(a.y, b.y);
    a.z = pkadd(a.z, b.z); a.w = pkadd(a.w, b.w);
    return a;
}

// XOR-swizzled f16 offset inside a [rows][128] f16 tile (r6-proven, 0 conflicts).
__device__ __forceinline__ int swz(int row, int k) {
    return row * 128 + ((((k >> 3) ^ (row & 15)) << 3) | (k & 7));
}

// ---------------- prep: weight cast/swizzle + zero row + degree count (fused) ----------------
// blocks 0..79: weight prep. block 80: zero row. blocks 81..3205: deg atomics (1.6M edges).

__global__ __launch_bounds__(512) void k_prep(const float* __restrict__ W1,
                                              const float* __restrict__ W2,
                                              const float* __restrict__ Wo,
                                              ushort* __restrict__ W1s,
                                              ushort* __restrict__ W2s,
                                              ushort* __restrict__ WoTs,
                                              ushort* __restrict__ h,
                                              const int* __restrict__ dst,
                                              int* __restrict__ deg) {
    const int b = blockIdx.x, t = threadIdx.x;
    if (b < 80) {
        int i = b * 512 + t;  // 0..40959
        if (i < 16384) {
            int k = i >> 7, n = i & 127;
            W1s[swz(n, k)] = f2h(W1[i]);
        } else if (i < 32768) {
            int j = i - 16384, k = j >> 7, n = j & 127;
            W2s[swz(n, k)] = f2h(W2[j]);
        } else {
            int j = i - 32768, k = j >> 6, n = j & 63;
            WoTs[swz(n, k)] = f2h(Wo[j]);
        }
    } else if (b == 80) {
        if (t < CH) h[(size_t)ZROW * CH + t] = 0;  // zero row for k_agg predication
    } else {
        int e = (b - 81) * 512 + t;  // 3125 blocks x 512 = 1.6M exact
        atomicAdd(&deg[dst[e]], 1);
    }
}

// ---------------- shared GEMM block body: out_f16[r] = rsqrt(deg[r]+1) * (A[r] @ W) --------
// 128 rows/block, 512 threads. Epilogue LDS-bounce -> 4 coalesced uint4 stores/thread.

template <typename IT>
__device__ __forceinline__ void gemm_block(int bidx, const IT* __restrict__ A,
                                           const ushort* __restrict__ Ws,
                                           const int* __restrict__ deg,
                                           ushort* __restrict__ out,
                                           ushort* sB, ushort* sA) {
    const int tid = threadIdx.x;
    const int row0 = bidx * 128;

    for (int i = tid; i < 2048; i += 512)
        ((float4*)sB)[i] = ((const float4*)Ws)[i];

    for (int i = tid; i < 4096; i += 512) {
        int m = i >> 5, u = i & 31, k4 = u << 2;
        int r = row0 + m;
        ushort4 pk = make_ushort4(0, 0, 0, 0);
        if (r < N_NODES) {
            if constexpr (sizeof(IT) == 4) {
                float4 a = ((const float4*)A)[r * 32 + u];
                pk = make_ushort4(f2h(a.x), f2h(a.y), f2h(a.z), f2h(a.w));
            } else {
                pk = ((const ushort4*)A)[r * 32 + u];
            }
        }
        *(ushort4*)&sA[swz(m, k4)] = pk;
    }
    __syncthreads();

    const int lane = tid & 63, wv = tid >> 6;
    const int mrow = lane & 15, quad = lane >> 4;
    f32x4 acc[8] = {};
#pragma unroll
    for (int kc = 0; kc < 4; ++kc) {
        int g = kc * 4 + quad;
        half8 a = *(const half8*)&sA[(wv * 16 + mrow) * 128 + ((g ^ mrow) << 3)];
#pragma unroll
        for (int nt = 0; nt < 8; ++nt) {
            half8 b = *(const half8*)&sB[(nt * 16 + mrow) * 128 + ((g ^ mrow) << 3)];
            acc[nt] = __builtin_amdgcn_mfma_f32_16x16x32_f16(a, b, acc[nt], 0, 0, 0);
        }
    }

    const int rbase4 = wv * 16 + quad * 4;
    float ds[4];
#pragma unroll
    for (int rg = 0; rg < 4; ++rg) {
        int r = row0 + rbase4 + rg;
        ds[rg] = (r < N_NODES) ? rsqrtf((float)(deg[r] + 1)) : 0.f;  // == old dis[r], bit-identical
    }

    __syncthreads();
#pragma unroll
    for (int nt = 0; nt < 8; ++nt) {
#pragma unroll
        for (int rg = 0; rg < 4; ++rg)
            sA[(rbase4 + rg) * 136 + nt * 16 + mrow] = f2h(acc[nt][rg] * ds[rg]);
    }
    __syncthreads();

#pragma unroll
    for (int k = 0; k < 4; ++k) {
        int idx = tid + k * 512;
        int m = idx >> 4, c16 = idx & 15;
        int r = row0 + m;
        if (r < N_NODES) {
            uint4 vv = *(const uint4*)&sA[m * 136 + c16 * 8];
            ((uint4*)out)[(size_t)r * 16 + c16] = vv;
        }
    }
}

// ---------------- fused: bin (blocks 0..390) + layer-1 GEMM (blocks 391..1172) -------------
// gemm1 depends only on W1s/deg (from k_prep), NOT on the CSR sort -> runs concurrently
// with the edge binning, taking gemm1 off the serial critical path.

__global__ __launch_bounds__(512) void k_bin_gemm(const int* __restrict__ src,
                                                  const int* __restrict__ dst,
                                                  int* __restrict__ bfill,
                                                  int* __restrict__ bin,
                                                  const float* __restrict__ A,
                                                  const ushort* __restrict__ Ws,
                                                  const int* __restrict__ deg,
                                                  ushort* __restrict__ out) {
    __shared__ __align__(16) char smem[32768 + 34816];  // gemm: sB|sA ; bin: hist|wbase|cur
    if (blockIdx.x < NBUCKET) {
        int* hist  = (int*)smem;
        int* wbase = (int*)(smem + 2048);
        int* cur   = (int*)(smem + 4096);
        const int t = threadIdx.x;
        const int e0 = blockIdx.x * BIN_CHUNK;

        hist[t] = 0;
        __syncthreads();

        int ss[8], bb[8], dl[8];
#pragma unroll
        for (int j = 0; j < 8; ++j) {
            int e = e0 + j * 512 + t;
            bb[j] = -1;
            if (e < N_EDGES) {
                int s = src[e], d = dst[e];
                ss[j] = s; dl[j] = d & 255; bb[j] = d >> 8;
                atomicAdd(&hist[bb[j]], 1);
            }
        }
        __syncthreads();

        int v = hist[t];
        for (int off = 1; off < 512; off <<= 1) {
            int tv = (t >= off) ? hist[t - off] : 0;
            __syncthreads();
            hist[t] += tv;
            __syncthreads();
        }
        int excl = hist[t] - v;
        if (t < NBUCKET && v > 0) {
            int gb = atomicAdd(&bfill[t], v);
            wbase[t] = gb - excl;
        }
        cur[t] = excl;
        __syncthreads();

#pragma unroll
        for (int j = 0; j < 8; ++j) {
            if (bb[j] >= 0) {
                int p = atomicAdd(&cur[bb[j]], 1);
                bin[bb[j] * CAP + wbase[bb[j]] + p] = (ss[j] << 8) | dl[j];
            }
        }
    } else {
        gemm_block<float>(blockIdx.x - NBUCKET, A, Ws, deg, out,
                          (ushort*)smem, (ushort*)(smem + 32768));
    }
}

// ---------------- standalone GEMM for layer 2 ----------------

template <typename IT>
__global__ __launch_bounds__(512) void k_gemm_mfma(const IT* __restrict__ A,
                                                   const ushort* __restrict__ Ws,
                                                   const int* __restrict__ deg,
                                                   ushort* __restrict__ out) {
    __shared__ __align__(16) char smem[32768 + 34816];
    gemm_block<IT>(blockIdx.x, A, Ws, deg, out, (ushort*)smem, (ushort*)(smem + 32768));
}

// ---------------- build: per-block redundant bucket scan + LDS counting sort ----------------
// The 391-entry bucket prefix scan is recomputed in every block (parallel, ~us) instead of
// a separate dependent dispatch. 512 threads halve the per-phase iteration counts.

__global__ __launch_bounds__(512) void k_build(const int* __restrict__ bfill,
                                               const int* __restrict__ bin,
                                               int* __restrict__ esrc,
                                               int2* __restrict__ scnt) {
    __shared__ int pre[512];
    __shared__ int cnt_l[256];
    __shared__ int cur_l[256];
    __shared__ int sortbuf[CAP];
    const int t = threadIdx.x;
    const int b = blockIdx.x;

    pre[t] = (t < NBUCKET) ? bfill[t] : 0;
    if (t < 256) cnt_l[t] = 0;
    __syncthreads();
    for (int off = 1; off < 512; off <<= 1) {
        int tv = (t >= off) ? pre[t - off] : 0;
        __syncthreads();
        pre[t] += tv;
        __syncthreads();
    }
    const int n = bfill[b];
    const int base = pre[b] - n;  // exclusive prefix
    const int* brec = bin + b * CAP;

    for (int i = t; i < n; i += 512)
        atomicAdd(&cnt_l[brec[i] & 255], 1);
    __syncthreads();

    int v = (t < 256) ? cnt_l[t] : 0;
    for (int off = 1; off < 256; off <<= 1) {
        int tv = (t >= off && t < 256) ? cnt_l[t - off] : 0;
        __syncthreads();
        if (t < 256) cnt_l[t] += tv;
        __syncthreads();
    }
    if (t < 256) {
        int excl = cnt_l[t] - v;
        int node = b * 256 + t;
        if (node < N_NODES) scnt[node] = make_int2(base + excl, v);
        cur_l[t] = excl;
    }
    __syncthreads();

    for (int i = t; i < n; i += 512) {
        int rec = brec[i];
        int p = atomicAdd(&cur_l[rec & 255], 1);
        sortbuf[p] = rec >> 8;
    }
    __syncthreads();
    for (int i = t; i < n; i += 512)
        esrc[base + i] = sortbuf[i];
}

// ---------------- CSR aggregation: 4 nodes/wave, depth-1 pipeline, predicated slots --------
// (r5-proven: 61.5 us, saturates the ~3.5 TB/s miss-path service rate)

struct Ictx { int n; int grp; int s0, s1, s2, s3, s4, s5; };
struct Gt { uint4 t0, t1, t2, t3, t4, t5, slf; };

__device__ __forceinline__ Ictx idx_stage(const int* __restrict__ esrc, int off, int n, int q) {
    Ictx c; c.n = n;
    const int* ep = esrc + off;
    // unconditional loads: stay inside the workspace (overread lands in the next ws buffer)
    int r0 = ep[q], r1 = ep[q + 4], r2 = ep[q + 8];
    int r3 = ep[q + 12], r4 = ep[q + 16], r5 = ep[q + 20];
    bool grp = (q + 12 < n);
    bool ok = (n <= q + 24);
    c.grp = grp;
    c.s0 = (grp || q < n)      ? r0 : ZROW;
    c.s1 = (grp || q + 4 < n)  ? r1 : ZROW;
    c.s2 = (grp || q + 8 < n)  ? r2 : ZROW;
    c.s3 = grp                 ? r3 : ZROW;
    c.s4 = (grp && ok && q + 16 < n) ? r4 : ZROW;
    c.s5 = (grp && ok && q + 20 < n) ? r5 : ZROW;
    return c;
}

__device__ __forceinline__ Gt gather_stage(const Ictx& c, int v, int l,
                                           const uint4* __restrict__ h16) {
    Gt g;
    g.t0 = h16[(size_t)c.s0 * 16 + l];
    g.t1 = h16[(size_t)c.s1 * 16 + l];
    g.t2 = h16[(size_t)c.s2 * 16 + l];
    g.t3 = h16[(size_t)c.s3 * 16 + l];
    g.t4 = h16[(size_t)c.s4 * 16 + l];
    g.t5 = h16[(size_t)c.s5 * 16 + l];
    g.slf = h16[(size_t)v * 16 + l];
    return g;
}

__device__ __forceinline__ void acc_finish(const Gt& g, const Ictx& c, int v, int q, int l,
                                           const int* __restrict__ esrc, int off,
                                           const uint4* __restrict__ h16,
                                           float dsv, float4 b0, float4 b1,
                                           ushort* __restrict__ out) {
    uint4 aA = make_uint4(0, 0, 0, 0), aB = make_uint4(0, 0, 0, 0);
    // exact r0 order: group -> aA,aB,aA,aB ; singles -> aA (invalid slots add +0)
    aA = pk4(aA, g.t0);
    if (c.grp) aB = pk4(aB, g.t1); else aA = pk4(aA, g.t1);
    aA = pk4(aA, g.t2);
    if (c.grp) aB = pk4(aB, g.t3); else aA = pk4(aA, g.t3);
    aA = pk4(aA, g.t4);
    aA = pk4(aA, g.t5);
    if (c.n > q + 24) {  // rare residual: exact r0 continuation from i = q+16
        const int* ep = esrc + off;
        int i = q + 16;
        for (; i + 12 < c.n; i += 16) {
            uint4 u0 = h16[(size_t)ep[i] * 16 + l];
            uint4 u1 = h16[(size_t)ep[i + 4] * 16 + l];
            uint4 u2 = h16[(size_t)ep[i + 8] * 16 + l];
            uint4 u3 = h16[(size_t)ep[i + 12] * 16 + l];
            aA = pk4(aA, u0); aB = pk4(aB, u1); aA = pk4(aA, u2); aB = pk4(aB, u3);
        }
        for (; i < c.n; i += 4) aA = pk4(aA, h16[(size_t)ep[i] * 16 + l]);
    }
    aA = pk4(aA, aB);
    // reduce across the 4 quarters
    aA.x = pkadd(aA.x, (uint)__shfl_xor((int)aA.x, 16));
    aA.y = pkadd(aA.y, (uint)__shfl_xor((int)aA.y, 16));
    aA.z = pkadd(aA.z, (uint)__shfl_xor((int)aA.z, 16));
    aA.w = pkadd(aA.w, (uint)__shfl_xor((int)aA.w, 16));
    aA.x = pkadd(aA.x, (uint)__shfl_xor((int)aA.x, 32));
    aA.y = pkadd(aA.y, (uint)__shfl_xor((int)aA.y, 32));
    aA.z = pkadd(aA.z, (uint)__shfl_xor((int)aA.z, 32));
    aA.w = pkadd(aA.w, (uint)__shfl_xor((int)aA.w, 32));

    if (q == 0) {
        aA = pk4(aA, g.slf);  // self-loop term h'[v] (prefetched)
        float2 a0 = __half22float2(*(__half2*)&aA.x);
        float2 a1 = __half22float2(*(__half2*)&aA.y);
        float2 a2 = __half22float2(*(__half2*)&aA.z);
        float2 a3 = __half22float2(*(__half2*)&aA.w);
        a0.x = fmaxf(a0.x * dsv + b0.x, 0.f); a0.y = fmaxf(a0.y * dsv + b0.y, 0.f);
        a1.x = fmaxf(a1.x * dsv + b0.z, 0.f); a1.y = fmaxf(a1.y * dsv + b0.w, 0.f);
        a2.x = fmaxf(a2.x * dsv + b1.x, 0.f); a2.y = fmaxf(a2.y * dsv + b1.y, 0.f);
        a3.x = fmaxf(a3.x * dsv + b1.z, 0.f); a3.y = fmaxf(a3.y * dsv + b1.w, 0.f);
        __half2 o0 = __float22half2_rn(a0);
        __half2 o1 = __float22half2_rn(a1);
        __half2 o2 = __float22half2_rn(a2);
        __half2 o3 = __float22half2_rn(a3);
        ((uint4*)out)[v * 16 + l] =
            make_uint4(*(uint*)&o0, *(uint*)&o1, *(uint*)&o2, *(uint*)&o3);
    }
}

__global__ __launch_bounds__(256) void k_agg(const int2* __restrict__ scnt,
                                             const int* __restrict__ esrc,
                                             const ushort* __restrict__ h,
                                             const int* __restrict__ deg,
                                             const float* __restrict__ bias,
                                             ushort* __restrict__ out) {
    const int w = threadIdx.x >> 6;
    const int vb = blockIdx.x * 16 + w * 4;  // 4 nodes per wave; grid exact (100000 = 6250*16)
    const int lane = threadIdx.x & 63, q = lane >> 4, l = lane & 15;
    const uint4* h16 = (const uint4*)h;

    // one-RT preload of all per-node meta + wave constants
    int2 m0 = scnt[vb], m1 = scnt[vb + 1], m2 = scnt[vb + 2], m3 = scnt[vb + 3];
    float d0 = rsqrtf((float)(deg[vb] + 1));      // == old dis[vb], bit-identical
    float d1 = rsqrtf((float)(deg[vb + 1] + 1));
    float d2 = rsqrtf((float)(deg[vb + 2] + 1));
    float d3 = rsqrtf((float)(deg[vb + 3] + 1));
    float4 b0 = ((const float4*)bias)[2 * l];
    float4 b1 = ((const float4*)bias)[2 * l + 1];

    Ictx c0 = idx_stage(esrc, m0.x, m0.y, q);
    Gt g0 = gather_stage(c0, vb, l, h16);
    Ictx c1 = idx_stage(esrc, m1.x, m1.y, q);
    Gt g1 = gather_stage(c1, vb + 1, l, h16);
    Ictx c2 = idx_stage(esrc, m2.x, m2.y, q);
    acc_finish(g0, c0, vb, q, l, esrc, m0.x, h16, d0, b0, b1, out);
    Gt g2 = gather_stage(c2, vb + 2, l, h16);
    Ictx c3 = idx_stage(esrc, m3.x, m3.y, q);
    acc_finish(g1, c1, vb + 1, q, l, esrc, m1.x, h16, d1, b0, b1, out);
    Gt g3 = gather_stage(c3, vb + 3, l, h16);
    acc_finish(g2, c2, vb + 2, q, l, esrc, m2.x, h16, d2, b0, b1, out);
    acc_finish(g3, c3, vb + 3, q, l, esrc, m3.x, h16, d3, b0, b1, out);
}

// ---------------- final MFMA: out_f32[N][64] = (x1+x2)@Wo + bo (r7-proven) ----------------

__global__ __launch_bounds__(512) void k_final_mfma(const ushort* __restrict__ x1,
                                                    const ushort* __restrict__ x2,
                                                    const ushort* __restrict__ Ws,
                                                    const float* __restrict__ bo,
                                                    float* __restrict__ out) {
    __shared__ ushort sB[64 * 128];   // 16 KB
    __shared__ float sF[128 * 68];    // 34.8 KB; low 32 KB aliased for f16 A staging
    ushort* sA = (ushort*)sF;
    const int tid = threadIdx.x;
    const int row0 = blockIdx.x * 128;

    for (int i = tid; i < 1024; i += 512)
        ((float4*)sB)[i] = ((const float4*)Ws)[i];

    for (int i = tid; i < 4096; i += 512) {
        int m = i >> 5, u = i & 31, k4 = u << 2;
        int r = row0 + m;
        uint2 pk = make_uint2(0, 0);
        if (r < N_NODES) {
            uint2 ua = ((const uint2*)x1)[r * 32 + u];
            uint2 ub = ((const uint2*)x2)[r * 32 + u];
            __half2 s0 = __hadd2(*(__half2*)&ua.x, *(__half2*)&ub.x);
            __half2 s1 = __hadd2(*(__half2*)&ua.y, *(__half2*)&ub.y);
            pk = make_uint2(*(uint*)&s0, *(uint*)&s1);
        }
        *(uint2*)&sA[swz(m, k4)] = pk;
    }
    __syncthreads();

    const int lane = tid & 63, wv = tid >> 6;
    const int mrow = lane & 15, quad = lane >> 4;
    f32x4 acc[4] = {};
#pragma unroll
    for (int kc = 0; kc < 4; ++kc) {
        int g = kc * 4 + quad;
        half8 a = *(const half8*)&sA[(wv * 16 + mrow) * 128 + ((g ^ mrow) << 3)];
#pragma unroll
        for (int nt = 0; nt < 4; ++nt) {
            half8 b = *(const half8*)&sB[(nt * 16 + mrow) * 128 + ((g ^ mrow) << 3)];
            acc[nt] = __builtin_amdgcn_mfma_f32_16x16x32_f16(a, b, acc[nt], 0, 0, 0);
        }
    }

    const int rbase4 = wv * 16 + quad * 4;
    __syncthreads();
#pragma unroll
    for (int nt = 0; nt < 4; ++nt) {
        float bb = bo[nt * 16 + mrow];
#pragma unroll
        for (int rg = 0; rg < 4; ++rg)
            sF[(rbase4 + rg) * 68 + nt * 16 + mrow] = acc[nt][rg] + bb;
    }
    __syncthreads();

#pragma unroll
    for (int k = 0; k < 4; ++k) {
        int idx = tid + k * 512;
        int m = idx >> 4, c16 = idx & 15;
        int r = row0 + m;
        if (r < N_NODES) {
            uint4 vv = *(const uint4*)&sF[m * 68 + c16 * 4];
            ((uint4*)out)[(size_t)r * 16 + c16] = vv;
        }
    }
}

// ---------------- launch ----------------

extern "C" void kernel_launch(void* const* d_in, const int* in_sizes, int n_in,
                              void* d_out, int out_size, void* d_ws, size_t ws_size,
                              hipStream_t stream) {
    const float* x  = (const float*)d_in[0];
    const int*   ei = (const int*)d_in[1];
    const int*   src = ei;
    const int*   dst = ei + N_EDGES;
    const float* W1 = (const float*)d_in[2];
    const float* b1 = (const float*)d_in[3];
    const float* W2 = (const float*)d_in[4];
    const float* b2 = (const float*)d_in[5];
    const float* Wo = (const float*)d_in[6];
    const float* bo = (const float*)d_in[7];
    float* out = (float*)d_out;

    char* ws = (char*)d_ws;
    int*    bfill  = (int*)ws;            ws += 2048;                      // memset with deg
    int*    deg    = (int*)ws;            ws += 400000;                    // contiguous w/ bfill
    int2*   scnt   = (int2*)ws;           ws += 800000;                    // packed (start,cnt)
    int*    bin    = (int*)ws;            ws += (size_t)NBUCKET * CAP * 4; // 12.8 MB
    int*    esrc   = (int*)ws;            ws += (size_t)N_EDGES * 4;
    ushort* W1s    = (ushort*)ws;         ws += 32768;
    ushort* W2s    = (ushort*)ws;         ws += 32768;
    ushort* WoTs   = (ushort*)ws;         ws += 16384;
    ushort* h      = (ushort*)ws;         ws += (size_t)(N_NODES + 1) * CH * 2;  // +1 zero row
    ushort* x1     = (ushort*)ws;         ws += (size_t)N_NODES * CH * 2;
    ushort* x2     = (ushort*)ws;

    const int gA = N_NODES / 16;           // 6250 (4 waves x 4 nodes per block)

    // prep (weights + zero row + degree) -> fused bin+gemm1 -> build (self-scan)
    hipMemsetAsync(bfill, 0, 2048 + 400000, stream);
    k_prep<<<81 + 3125, 512, 0, stream>>>(W1, W2, Wo, W1s, W2s, WoTs, h, dst, deg);
    k_bin_gemm<<<NBUCKET + GG, 512, 0, stream>>>(src, dst, bfill, bin, x, W1s, deg, h);
    k_build<<<NBUCKET, 512, 0, stream>>>(bfill, bin, esrc, scnt);

    // layer 1 aggregation
    k_agg<<<gA, 256, 0, stream>>>(scnt, esrc, h, deg, b1, x1);

    // layer 2
    k_gemm_mfma<ushort><<<GG, 512, 0, stream>>>(x1, W2s, deg, h);
    k_agg<<<gA, 256, 0, stream>>>(scnt, esrc, h, deg, b2, x2);

    // output projection
    k_final_mfma<<<GG, 512, 0, stream>>>(x1, x2, WoTs, bo, out);
}

// Round 9
// 297.723 us; speedup vs baseline: 1.2246x; 1.2246x over previous
//
#include <hip/hip_runtime.h>
#include <hip/hip_fp16.h>

#define N_NODES 100000
#define N_EDGES 1600000
#define CH 128
#define OCH 64
#define NBUCKET 391   // ceil(100000/256) dst-buckets of 256 nodes
#define CAP 8192      // bucket capacity (mean 4092, sd ~64)
#define BIN_CHUNK 4096
#define ZROW N_NODES  // index of the guaranteed-zero h row (predication target)
#define GG 782        // ceil(100000/128) gemm blocks

typedef _Float16 half8 __attribute__((ext_vector_type(8)));
typedef float f32x4 __attribute__((ext_vector_type(4)));

__device__ __forceinline__ ushort f2h(float f) {
    _Float16 h = (_Float16)f;
    return *(ushort*)&h;
}

__device__ __forceinline__ uint pkadd(uint a, uint b) {
    __half2 r = __hadd2(*(__half2*)&a, *(__half2*)&b);
    return *(uint*)&r;
}

__device__ __forceinline__ uint4 pk4(uint4 a, uint4 b) {
    a.x = pkadd(a.x, b.x); a.y = pkadd(a.y, b.y);
    a.z = pkadd(a.z, b.z); a.w = pkadd(a.w, b.w);
    return a;
}

// XOR-swizzled f16 offset inside a [rows][128] f16 tile (r6-proven, 0 conflicts).
__device__ __forceinline__ int swz(int row, int k) {
    return row * 128 + ((((k >> 3) ^ (row & 15)) << 3) | (k & 7));
}

// ---------------- fused: bin (blocks 0..390, full LDS sort + coalesced run writes)
// ----------------        + weight prep (391..470) + zero row (471) ----------------
// The bin path sorts its 4096 edges by bucket ENTIRELY in LDS, then writes each
// bucket's run contiguously -> consecutive lanes hit consecutive addresses
// (vs r7's 1.6M random 4B scatter stores = ~100 MB write-allocate traffic).

__global__ __launch_bounds__(512) void k_bin_prep(const int* __restrict__ src,
                                                  const int* __restrict__ dst,
                                                  int* __restrict__ bfill,
                                                  int* __restrict__ bin,
                                                  const float* __restrict__ W1,
                                                  const float* __restrict__ W2,
                                                  const float* __restrict__ Wo,
                                                  ushort* __restrict__ W1s,
                                                  ushort* __restrict__ W2s,
                                                  ushort* __restrict__ WoTs,
                                                  ushort* __restrict__ h) {
    __shared__ int hist[512];
    __shared__ int excl[512];
    __shared__ int wbase[512];
    __shared__ int cur[512];
    __shared__ int sbuf[BIN_CHUNK];
    __shared__ ushort sbkt[BIN_CHUNK];
    const int t = threadIdx.x;

    if (blockIdx.x >= NBUCKET) {
        int b = blockIdx.x - NBUCKET;
        if (b == 80) {
            if (t < CH) h[(size_t)ZROW * CH + t] = 0;  // zero row for k_agg predication
        } else {
            int i = b * 512 + t;  // 0..40959
            if (i < 16384) {
                int k = i >> 7, n = i & 127;
                W1s[swz(n, k)] = f2h(W1[i]);
            } else if (i < 32768) {
                int j = i - 16384, k = j >> 7, n = j & 127;
                W2s[swz(n, k)] = f2h(W2[j]);
            } else {
                int j = i - 32768, k = j >> 6, n = j & 63;
                WoTs[swz(n, k)] = f2h(Wo[j]);
            }
        }
        return;
    }

    const int e0 = blockIdx.x * BIN_CHUNK;
    hist[t] = 0;
    __syncthreads();

    int ss[8], bb[8], dl[8];
#pragma unroll
    for (int j = 0; j < 8; ++j) {
        int e = e0 + j * 512 + t;
        bb[j] = -1;
        if (e < N_EDGES) {
            int s = src[e], d = dst[e];
            ss[j] = s; dl[j] = d & 255; bb[j] = d >> 8;
            atomicAdd(&hist[bb[j]], 1);
        }
    }
    __syncthreads();

    int v = hist[t];
    for (int off = 1; off < 512; off <<= 1) {
        int tv = (t >= off) ? hist[t - off] : 0;
        __syncthreads();
        hist[t] += tv;
        __syncthreads();
    }
    int ex = hist[t] - v;
    excl[t] = ex;
    cur[t] = ex;
    if (t < NBUCKET && v > 0) wbase[t] = atomicAdd(&bfill[t], v);
    __syncthreads();

#pragma unroll
    for (int j = 0; j < 8; ++j) {
        if (bb[j] >= 0) {
            int p = atomicAdd(&cur[bb[j]], 1);
            sbuf[p] = (ss[j] << 8) | dl[j];
            sbkt[p] = (ushort)bb[j];
        }
    }
    const int nloc = hist[511];
    __syncthreads();

    // run-contiguous write-out: consecutive i -> consecutive bin addresses
    for (int i = t; i < nloc; i += 512) {
        int b = sbkt[i];
        bin[b * CAP + wbase[b] + (i - excl[b])] = sbuf[i];
    }
}

// ---------------- build: per-block redundant bucket scan + LDS counting sort ----------------
// Produces scnt (start,cnt) and dis = rsqrt(cnt+1) — bit-identical to the r7 path.

__global__ __launch_bounds__(512) void k_build(const int* __restrict__ bfill,
                                               const int* __restrict__ bin,
                                               int* __restrict__ esrc,
                                               int2* __restrict__ scnt,
                                               float* __restrict__ dis) {
    __shared__ int pre[512];
    __shared__ int cnt_l[256];
    __shared__ int cur_l[256];
    __shared__ int sortbuf[CAP];
    const int t = threadIdx.x;
    const int b = blockIdx.x;

    pre[t] = (t < NBUCKET) ? bfill[t] : 0;
    if (t < 256) cnt_l[t] = 0;
    __syncthreads();
    for (int off = 1; off < 512; off <<= 1) {
        int tv = (t >= off) ? pre[t - off] : 0;
        __syncthreads();
        pre[t] += tv;
        __syncthreads();
    }
    const int n = bfill[b];
    const int base = pre[b] - n;  // exclusive prefix
    const int* brec = bin + b * CAP;

    for (int i = t; i < n; i += 512)
        atomicAdd(&cnt_l[brec[i] & 255], 1);
    __syncthreads();

    int v = (t < 256) ? cnt_l[t] : 0;
    for (int off = 1; off < 256; off <<= 1) {
        int tv = (t >= off && t < 256) ? cnt_l[t - off] : 0;
        __syncthreads();
        if (t < 256) cnt_l[t] += tv;
        __syncthreads();
    }
    if (t < 256) {
        int excl = cnt_l[t] - v;
        int node = b * 256 + t;
        if (node < N_NODES) {
            scnt[node] = make_int2(base + excl, v);
            dis[node] = rsqrtf((float)(v + 1));  // +1 self-loop
        }
        cur_l[t] = excl;
    }
    __syncthreads();

    for (int i = t; i < n; i += 512) {
        int rec = brec[i];
        int p = atomicAdd(&cur_l[rec & 255], 1);
        sortbuf[p] = rec >> 8;
    }
    __syncthreads();
    for (int i = t; i < n; i += 512)
        esrc[base + i] = sortbuf[i];
}

// ---------------- MFMA GEMM: out_f16[r] = dis[r] * (A[r] @ W) (r7-proven) ----------------
// 128 rows/block, 512 threads. Epilogue LDS-bounce -> 4 coalesced uint4 stores/thread.

template <typename IT>
__global__ __launch_bounds__(512) void k_gemm_mfma(const IT* __restrict__ A,
                                                   const ushort* __restrict__ Ws,
                                                   const float* __restrict__ dis,
                                                   ushort* __restrict__ out) {
    __shared__ ushort sB[128 * 128];   // 32 KB
    __shared__ ushort sA[128 * 136];   // 34.8 KB; MFMA phase uses stride-128 region
    const int tid = threadIdx.x;
    const int row0 = blockIdx.x * 128;

    for (int i = tid; i < 2048; i += 512)
        ((float4*)sB)[i] = ((const float4*)Ws)[i];

    for (int i = tid; i < 4096; i += 512) {
        int m = i >> 5, u = i & 31, k4 = u << 2;
        int r = row0 + m;
        ushort4 pk = make_ushort4(0, 0, 0, 0);
        if (r < N_NODES) {
            if constexpr (sizeof(IT) == 4) {
                float4 a = ((const float4*)A)[r * 32 + u];
                pk = make_ushort4(f2h(a.x), f2h(a.y), f2h(a.z), f2h(a.w));
            } else {
                pk = ((const ushort4*)A)[r * 32 + u];
            }
        }
        *(ushort4*)&sA[swz(m, k4)] = pk;
    }
    __syncthreads();

    const int lane = tid & 63, wv = tid >> 6;
    const int mrow = lane & 15, quad = lane >> 4;
    f32x4 acc[8] = {};
#pragma unroll
    for (int kc = 0; kc < 4; ++kc) {
        int g = kc * 4 + quad;
        half8 a = *(const half8*)&sA[(wv * 16 + mrow) * 128 + ((g ^ mrow) << 3)];
#pragma unroll
        for (int nt = 0; nt < 8; ++nt) {
            half8 b = *(const half8*)&sB[(nt * 16 + mrow) * 128 + ((g ^ mrow) << 3)];
            acc[nt] = __builtin_amdgcn_mfma_f32_16x16x32_f16(a, b, acc[nt], 0, 0, 0);
        }
    }

    const int rbase4 = wv * 16 + quad * 4;
    float ds[4];
#pragma unroll
    for (int rg = 0; rg < 4; ++rg) {
        int r = row0 + rbase4 + rg;
        ds[rg] = (r < N_NODES) ? dis[r] : 0.f;
    }

    __syncthreads();
#pragma unroll
    for (int nt = 0; nt < 8; ++nt) {
#pragma unroll
        for (int rg = 0; rg < 4; ++rg)
            sA[(rbase4 + rg) * 136 + nt * 16 + mrow] = f2h(acc[nt][rg] * ds[rg]);
    }
    __syncthreads();

#pragma unroll
    for (int k = 0; k < 4; ++k) {
        int idx = tid + k * 512;
        int m = idx >> 4, c16 = idx & 15;
        int r = row0 + m;
        if (r < N_NODES) {
            uint4 vv = *(const uint4*)&sA[m * 136 + c16 * 8];
            ((uint4*)out)[(size_t)r * 16 + c16] = vv;
        }
    }
}

// ---------------- CSR aggregation: 4 nodes/wave, depth-1 pipeline, predicated slots --------
// (r5-proven: 61.5 us, saturates the ~3.5 TB/s L3 miss-path service rate)

struct Ictx { int n; int grp; int s0, s1, s2, s3, s4, s5; };
struct Gt { uint4 t0, t1, t2, t3, t4, t5, slf; };

__device__ __forceinline__ Ictx idx_stage(const int* __restrict__ esrc, int off, int n, int q) {
    Ictx c; c.n = n;
    const int* ep = esrc + off;
    // unconditional loads: stay inside the workspace (overread lands in the next ws buffer)
    int r0 = ep[q], r1 = ep[q + 4], r2 = ep[q + 8];
    int r3 = ep[q + 12], r4 = ep[q + 16], r5 = ep[q + 20];
    bool grp = (q + 12 < n);
    bool ok = (n <= q + 24);
    c.grp = grp;
    c.s0 = (grp || q < n)      ? r0 : ZROW;
    c.s1 = (grp || q + 4 < n)  ? r1 : ZROW;
    c.s2 = (grp || q + 8 < n)  ? r2 : ZROW;
    c.s3 = grp                 ? r3 : ZROW;
    c.s4 = (grp && ok && q + 16 < n) ? r4 : ZROW;
    c.s5 = (grp && ok && q + 20 < n) ? r5 : ZROW;
    return c;
}

__device__ __forceinline__ Gt gather_stage(const Ictx& c, int v, int l,
                                           const uint4* __restrict__ h16) {
    Gt g;
    g.t0 = h16[(size_t)c.s0 * 16 + l];
    g.t1 = h16[(size_t)c.s1 * 16 + l];
    g.t2 = h16[(size_t)c.s2 * 16 + l];
    g.t3 = h16[(size_t)c.s3 * 16 + l];
    g.t4 = h16[(size_t)c.s4 * 16 + l];
    g.t5 = h16[(size_t)c.s5 * 16 + l];
    g.slf = h16[(size_t)v * 16 + l];
    return g;
}

__device__ __forceinline__ void acc_finish(const Gt& g, const Ictx& c, int v, int q, int l,
                                           const int* __restrict__ esrc, int off,
                                           const uint4* __restrict__ h16,
                                           float dsv, float4 b0, float4 b1,
                                           ushort* __restrict__ out) {
    uint4 aA = make_uint4(0, 0, 0, 0), aB = make_uint4(0, 0, 0, 0);
    // exact r0 order: group -> aA,aB,aA,aB ; singles -> aA (invalid slots add +0)
    aA = pk4(aA, g.t0);
    if (c.grp) aB = pk4(aB, g.t1); else aA = pk4(aA, g.t1);
    aA = pk4(aA, g.t2);
    if (c.grp) aB = pk4(aB, g.t3); else aA = pk4(aA, g.t3);
    aA = pk4(aA, g.t4);
    aA = pk4(aA, g.t5);
    if (c.n > q + 24) {  // rare residual: exact r0 continuation from i = q+16
        const int* ep = esrc + off;
        int i = q + 16;
        for (; i + 12 < c.n; i += 16) {
            uint4 u0 = h16[(size_t)ep[i] * 16 + l];
            uint4 u1 = h16[(size_t)ep[i + 4] * 16 + l];
            uint4 u2 = h16[(size_t)ep[i + 8] * 16 + l];
            uint4 u3 = h16[(size_t)ep[i + 12] * 16 + l];
            aA = pk4(aA, u0); aB = pk4(aB, u1); aA = pk4(aA, u2); aB = pk4(aB, u3);
        }
        for (; i < c.n; i += 4) aA = pk4(aA, h16[(size_t)ep[i] * 16 + l]);
    }
    aA = pk4(aA, aB);
    // reduce across the 4 quarters
    aA.x = pkadd(aA.x, (uint)__shfl_xor((int)aA.x, 16));
    aA.y = pkadd(aA.y, (uint)__shfl_xor((int)aA.y, 16));
    aA.z = pkadd(aA.z, (uint)__shfl_xor((int)aA.z, 16));
    aA.w = pkadd(aA.w, (uint)__shfl_xor((int)aA.w, 16));
    aA.x = pkadd(aA.x, (uint)__shfl_xor((int)aA.x, 32));
    aA.y = pkadd(aA.y, (uint)__shfl_xor((int)aA.y, 32));
    aA.z = pkadd(aA.z, (uint)__shfl_xor((int)aA.z, 32));
    aA.w = pkadd(aA.w, (uint)__shfl_xor((int)aA.w, 32));

    if (q == 0) {
        aA = pk4(aA, g.slf);  // self-loop term h'[v] (prefetched)
        float2 a0 = __half22float2(*(__half2*)&aA.x);
        float2 a1 = __half22float2(*(__half2*)&aA.y);
        float2 a2 = __half22float2(*(__half2*)&aA.z);
        float2 a3 = __half22float2(*(__half2*)&aA.w);
        a0.x = fmaxf(a0.x * dsv + b0.x, 0.f); a0.y = fmaxf(a0.y * dsv + b0.y, 0.f);
        a1.x = fmaxf(a1.x * dsv + b0.z, 0.f); a1.y = fmaxf(a1.y * dsv + b0.w, 0.f);
        a2.x = fmaxf(a2.x * dsv + b1.x, 0.f); a2.y = fmaxf(a2.y * dsv + b1.y, 0.f);
        a3.x = fmaxf(a3.x * dsv + b1.z, 0.f); a3.y = fmaxf(a3.y * dsv + b1.w, 0.f);
        __half2 o0 = __float22half2_rn(a0);
        __half2 o1 = __float22half2_rn(a1);
        __half2 o2 = __float22half2_rn(a2);
        __half2 o3 = __float22half2_rn(a3);
        ((uint4*)out)[v * 16 + l] =
            make_uint4(*(uint*)&o0, *(uint*)&o1, *(uint*)&o2, *(uint*)&o3);
    }
}

__global__ __launch_bounds__(256) void k_agg(const int2* __restrict__ scnt,
                                             const int* __restrict__ esrc,
                                             const ushort* __restrict__ h,
                                             const float* __restrict__ dis,
                                             const float* __restrict__ bias,
                                             ushort* __restrict__ out) {
    const int w = threadIdx.x >> 6;
    const int vb = blockIdx.x * 16 + w * 4;  // 4 nodes per wave; grid exact (100000 = 6250*16)
    const int lane = threadIdx.x & 63, q = lane >> 4, l = lane & 15;
    const uint4* h16 = (const uint4*)h;

    // one-RT preload of all per-node meta + wave constants
    int2 m0 = scnt[vb], m1 = scnt[vb + 1], m2 = scnt[vb + 2], m3 = scnt[vb + 3];
    float d0 = dis[vb], d1 = dis[vb + 1], d2 = dis[vb + 2], d3 = dis[vb + 3];
    float4 b0 = ((const float4*)bias)[2 * l];
    float4 b1 = ((const float4*)bias)[2 * l + 1];

    Ictx c0 = idx_stage(esrc, m0.x, m0.y, q);
    Gt g0 = gather_stage(c0, vb, l, h16);
    Ictx c1 = idx_stage(esrc, m1.x, m1.y, q);
    Gt g1 = gather_stage(c1, vb + 1, l, h16);
    Ictx c2 = idx_stage(esrc, m2.x, m2.y, q);
    acc_finish(g0, c0, vb, q, l, esrc, m0.x, h16, d0, b0, b1, out);
    Gt g2 = gather_stage(c2, vb + 2, l, h16);
    Ictx c3 = idx_stage(esrc, m3.x, m3.y, q);
    acc_finish(g1, c1, vb + 1, q, l, esrc, m1.x, h16, d1, b0, b1, out);
    Gt g3 = gather_stage(c3, vb + 3, l, h16);
    acc_finish(g2, c2, vb + 2, q, l, esrc, m2.x, h16, d2, b0, b1, out);
    acc_finish(g3, c3, vb + 3, q, l, esrc, m3.x, h16, d3, b0, b1, out);
}

// ---------------- final MFMA: out_f32[N][64] = (x1+x2)@Wo + bo (r7-proven) ----------------

__global__ __launch_bounds__(512) void k_final_mfma(const ushort* __restrict__ x1,
                                                    const ushort* __restrict__ x2,
                                                    const ushort* __restrict__ Ws,
                                                    const float* __restrict__ bo,
                                                    float* __restrict__ out) {
    __shared__ ushort sB[64 * 128];   // 16 KB
    __shared__ float sF[128 * 68];    // 34.8 KB; low 32 KB aliased for f16 A staging
    ushort* sA = (ushort*)sF;
    const int tid = threadIdx.x;
    const int row0 = blockIdx.x * 128;

    for (int i = tid; i < 1024; i += 512)
        ((float4*)sB)[i] = ((const float4*)Ws)[i];

    for (int i = tid; i < 4096; i += 512) {
        int m = i >> 5, u = i & 31, k4 = u << 2;
        int r = row0 + m;
        uint2 pk = make_uint2(0, 0);
        if (r < N_NODES) {
            uint2 ua = ((const uint2*)x1)[r * 32 + u];
            uint2 ub = ((const uint2*)x2)[r * 32 + u];
            __half2 s0 = __hadd2(*(__half2*)&ua.x, *(__half2*)&ub.x);
            __half2 s1 = __hadd2(*(__half2*)&ua.y, *(__half2*)&ub.y);
            pk = make_uint2(*(uint*)&s0, *(uint*)&s1);
        }
        *(uint2*)&sA[swz(m, k4)] = pk;
    }
    __syncthreads();

    const int lane = tid & 63, wv = tid >> 6;
    const int mrow = lane & 15, quad = lane >> 4;
    f32x4 acc[4] = {};
#pragma unroll
    for (int kc = 0; kc < 4; ++kc) {
        int g = kc * 4 + quad;
        half8 a = *(const half8*)&sA[(wv * 16 + mrow) * 128 + ((g ^ mrow) << 3)];
#pragma unroll
        for (int nt = 0; nt < 4; ++nt) {
            half8 b = *(const half8*)&sB[(nt * 16 + mrow) * 128 + ((g ^ mrow) << 3)];
            acc[nt] = __builtin_amdgcn_mfma_f32_16x16x32_f16(a, b, acc[nt], 0, 0, 0);
        }
    }

    const int rbase4 = wv * 16 + quad * 4;
    __syncthreads();
#pragma unroll
    for (int nt = 0; nt < 4; ++nt) {
        float bb = bo[nt * 16 + mrow];
#pragma unroll
        for (int rg = 0; rg < 4; ++rg)
            sF[(rbase4 + rg) * 68 + nt * 16 + mrow] = acc[nt][rg] + bb;
    }
    __syncthreads();

#pragma unroll
    for (int k = 0; k < 4; ++k) {
        int idx = tid + k * 512;
        int m = idx >> 4, c16 = idx & 15;
        int r = row0 + m;
        if (r < N_NODES) {
            uint4 vv = *(const uint4*)&sF[m * 68 + c16 * 4];
            ((uint4*)out)[(size_t)r * 16 + c16] = vv;
        }
    }
}

// ---------------- launch ----------------

extern "C" void kernel_launch(void* const* d_in, const int* in_sizes, int n_in,
                              void* d_out, int out_size, void* d_ws, size_t ws_size,
                              hipStream_t stream) {
    const float* x  = (const float*)d_in[0];
    const int*   ei = (const int*)d_in[1];
    const int*   src = ei;
    const int*   dst = ei + N_EDGES;
    const float* W1 = (const float*)d_in[2];
    const float* b1 = (const float*)d_in[3];
    const float* W2 = (const float*)d_in[4];
    const float* b2 = (const float*)d_in[5];
    const float* Wo = (const float*)d_in[6];
    const float* bo = (const float*)d_in[7];
    float* out = (float*)d_out;

    char* ws = (char*)d_ws;
    int*    bfill  = (int*)ws;            ws += 2048;
    int2*   scnt   = (int2*)ws;           ws += 800000;                    // packed (start,cnt)
    float*  dis    = (float*)ws;          ws += 400000;
    int*    bin    = (int*)ws;            ws += (size_t)NBUCKET * CAP * 4; // 12.8 MB
    int*    esrc   = (int*)ws;            ws += (size_t)N_EDGES * 4;
    ushort* W1s    = (ushort*)ws;         ws += 32768;
    ushort* W2s    = (ushort*)ws;         ws += 32768;
    ushort* WoTs   = (ushort*)ws;         ws += 16384;
    ushort* h      = (ushort*)ws;         ws += (size_t)(N_NODES + 1) * CH * 2;  // +1 zero row
    ushort* x1     = (ushort*)ws;         ws += (size_t)N_NODES * CH * 2;
    ushort* x2     = (ushort*)ws;

    const int gA = N_NODES / 16;           // 6250 (4 waves x 4 nodes per block)

    // CSR build: memset -> fused bin+prep -> build (self-scan, emits scnt + dis)
    hipMemsetAsync(bfill, 0, 2048, stream);
    k_bin_prep<<<NBUCKET + 81, 512, 0, stream>>>(src, dst, bfill, bin,
                                                 W1, W2, Wo, W1s, W2s, WoTs, h);
    k_build<<<NBUCKET, 512, 0, stream>>>(bfill, bin, esrc, scnt, dis);

    // layer 1
    k_gemm_mfma<float><<<GG, 512, 0, stream>>>(x, W1s, dis, h);
    k_agg<<<gA, 256, 0, stream>>>(scnt, esrc, h, dis, b1, x1);

    // layer 2
    k_gemm_mfma<ushort><<<GG, 512, 0, stream>>>(x1, W2s, dis, h);
    k_agg<<<gA, 256, 0, stream>>>(scnt, esrc, h, dis, b2, x2);

    // output projection
    k_final_mfma<<<GG, 512, 0, stream>>>(x1, x2, WoTs, bo, out);
}

// Round 10
// 276.000 us; speedup vs baseline: 1.3210x; 1.0787x over previous
//
#include <hip/hip_runtime.h>
#include <hip/hip_fp16.h>

#define N_NODES 100000
#define N_EDGES 1600000
#define CH 128
#define OCH 64
#define NBUCKET 391   // ceil(100000/256) dst-buckets of 256 nodes
#define CAP 8192      // bucket capacity (mean 4092, sd ~64)
#define BIN_CHUNK 4096
#define ZROW N_NODES  // index of the guaranteed-zero h row (predication target)
#define GG 782        // ceil(100000/128) gemm blocks

typedef _Float16 half8 __attribute__((ext_vector_type(8)));
typedef float f32x4 __attribute__((ext_vector_type(4)));

__device__ __forceinline__ ushort f2h(float f) {
    _Float16 h = (_Float16)f;
    return *(ushort*)&h;
}

__device__ __forceinline__ uint pkadd(uint a, uint b) {
    __half2 r = __hadd2(*(__half2*)&a, *(__half2*)&b);
    return *(uint*)&r;
}

__device__ __forceinline__ uint4 pk4(uint4 a, uint4 b) {
    a.x = pkadd(a.x, b.x); a.y = pkadd(a.y, b.y);
    a.z = pkadd(a.z, b.z); a.w = pkadd(a.w, b.w);
    return a;
}

// XOR-swizzled f16 offset inside a [rows][128] f16 tile (r6-proven, 0 conflicts).
__device__ __forceinline__ int swz(int row, int k) {
    return row * 128 + ((((k >> 3) ^ (row & 15)) << 3) | (k & 7));
}

// ---------------- fused: bin (blocks 0..390, LDS sort + coalesced run writes)
// ----------------        + weight prep (391..470) + zero rows (471) ----------------

__global__ __launch_bounds__(512) void k_bin_prep(const int* __restrict__ src,
                                                  const int* __restrict__ dst,
                                                  int* __restrict__ bfill,
                                                  int* __restrict__ bin,
                                                  const float* __restrict__ W1,
                                                  const float* __restrict__ W2,
                                                  const float* __restrict__ Wo,
                                                  ushort* __restrict__ W1s,
                                                  ushort* __restrict__ W2s,
                                                  ushort* __restrict__ WoTs,
                                                  ushort* __restrict__ h,
                                                  ushort* __restrict__ h2) {
    __shared__ int hist[512];
    __shared__ int excl[512];
    __shared__ int wbase[512];
    __shared__ int cur[512];
    __shared__ int sbuf[BIN_CHUNK];
    __shared__ ushort sbkt[BIN_CHUNK];
    const int t = threadIdx.x;

    if (blockIdx.x >= NBUCKET) {
        int b = blockIdx.x - NBUCKET;
        if (b == 80) {
            if (t < CH) {
                h[(size_t)ZROW * CH + t] = 0;   // zero rows for k_agg predication
                h2[(size_t)ZROW * CH + t] = 0;
            }
        } else {
            int i = b * 512 + t;  // 0..40959
            if (i < 16384) {
                int k = i >> 7, n = i & 127;
                W1s[swz(n, k)] = f2h(W1[i]);
            } else if (i < 32768) {
                int j = i - 16384, k = j >> 7, n = j & 127;
                W2s[swz(n, k)] = f2h(W2[j]);
            } else {
                int j = i - 32768, k = j >> 6, n = j & 63;
                WoTs[swz(n, k)] = f2h(Wo[j]);
            }
        }
        return;
    }

    const int e0 = blockIdx.x * BIN_CHUNK;
    hist[t] = 0;
    __syncthreads();

    int ss[8], bb[8], dl[8];
#pragma unroll
    for (int j = 0; j < 8; ++j) {
        int e = e0 + j * 512 + t;
        bb[j] = -1;
        if (e < N_EDGES) {
            int s = src[e], d = dst[e];
            ss[j] = s; dl[j] = d & 255; bb[j] = d >> 8;
            atomicAdd(&hist[bb[j]], 1);
        }
    }
    __syncthreads();

    int v = hist[t];
    for (int off = 1; off < 512; off <<= 1) {
        int tv = (t >= off) ? hist[t - off] : 0;
        __syncthreads();
        hist[t] += tv;
        __syncthreads();
    }
    int ex = hist[t] - v;
    excl[t] = ex;
    cur[t] = ex;
    if (t < NBUCKET && v > 0) wbase[t] = atomicAdd(&bfill[t], v);
    __syncthreads();

#pragma unroll
    for (int j = 0; j < 8; ++j) {
        if (bb[j] >= 0) {
            int p = atomicAdd(&cur[bb[j]], 1);
            sbuf[p] = (ss[j] << 8) | dl[j];
            sbkt[p] = (ushort)bb[j];
        }
    }
    const int nloc = hist[511];
    __syncthreads();

    for (int i = t; i < nloc; i += 512) {
        int b = sbkt[i];
        bin[b * CAP + wbase[b] + (i - excl[b])] = sbuf[i];
    }
}

// ---------------- build: per-block redundant bucket scan + LDS counting sort ----------------

__global__ __launch_bounds__(512) void k_build(const int* __restrict__ bfill,
                                               const int* __restrict__ bin,
                                               int* __restrict__ esrc,
                                               int2* __restrict__ scnt,
                                               float* __restrict__ dis) {
    __shared__ int pre[512];
    __shared__ int cnt_l[256];
    __shared__ int cur_l[256];
    __shared__ int sortbuf[CAP];
    const int t = threadIdx.x;
    const int b = blockIdx.x;

    pre[t] = (t < NBUCKET) ? bfill[t] : 0;
    if (t < 256) cnt_l[t] = 0;
    __syncthreads();
    for (int off = 1; off < 512; off <<= 1) {
        int tv = (t >= off) ? pre[t - off] : 0;
        __syncthreads();
        pre[t] += tv;
        __syncthreads();
    }
    const int n = bfill[b];
    const int base = pre[b] - n;  // exclusive prefix
    const int* brec = bin + b * CAP;

    for (int i = t; i < n; i += 512)
        atomicAdd(&cnt_l[brec[i] & 255], 1);
    __syncthreads();

    int v = (t < 256) ? cnt_l[t] : 0;
    for (int off = 1; off < 256; off <<= 1) {
        int tv = (t >= off && t < 256) ? cnt_l[t - off] : 0;
        __syncthreads();
        if (t < 256) cnt_l[t] += tv;
        __syncthreads();
    }
    if (t < 256) {
        int excl = cnt_l[t] - v;
        int node = b * 256 + t;
        if (node < N_NODES) {
            scnt[node] = make_int2(base + excl, v);
            dis[node] = rsqrtf((float)(v + 1));  // +1 self-loop
        }
        cur_l[t] = excl;
    }
    __syncthreads();

    for (int i = t; i < n; i += 512) {
        int rec = brec[i];
        int p = atomicAdd(&cur_l[rec & 255], 1);
        sortbuf[p] = rec >> 8;
    }
    __syncthreads();
    for (int i = t; i < n; i += 512)
        esrc[base + i] = sortbuf[i];
}

// ---------------- MFMA GEMM (layer 1 only): h[r] = dis[r] * (x[r] @ W1) (r7-proven) -------

__global__ __launch_bounds__(512) void k_gemm_mfma(const float* __restrict__ A,
                                                   const ushort* __restrict__ Ws,
                                                   const float* __restrict__ dis,
                                                   ushort* __restrict__ out) {
    __shared__ ushort sB[128 * 128];
    __shared__ ushort sA[128 * 136];
    const int tid = threadIdx.x;
    const int row0 = blockIdx.x * 128;

    for (int i = tid; i < 2048; i += 512)
        ((float4*)sB)[i] = ((const float4*)Ws)[i];

    for (int i = tid; i < 4096; i += 512) {
        int m = i >> 5, u = i & 31, k4 = u << 2;
        int r = row0 + m;
        ushort4 pk = make_ushort4(0, 0, 0, 0);
        if (r < N_NODES) {
            float4 a = ((const float4*)A)[r * 32 + u];
            pk = make_ushort4(f2h(a.x), f2h(a.y), f2h(a.z), f2h(a.w));
        }
        *(ushort4*)&sA[swz(m, k4)] = pk;
    }
    __syncthreads();

    const int lane = tid & 63, wv = tid >> 6;
    const int mrow = lane & 15, quad = lane >> 4;
    f32x4 acc[8] = {};
#pragma unroll
    for (int kc = 0; kc < 4; ++kc) {
        int g = kc * 4 + quad;
        half8 a = *(const half8*)&sA[(wv * 16 + mrow) * 128 + ((g ^ mrow) << 3)];
#pragma unroll
        for (int nt = 0; nt < 8; ++nt) {
            half8 b = *(const half8*)&sB[(nt * 16 + mrow) * 128 + ((g ^ mrow) << 3)];
            acc[nt] = __builtin_amdgcn_mfma_f32_16x16x32_f16(a, b, acc[nt], 0, 0, 0);
        }
    }

    const int rbase4 = wv * 16 + quad * 4;
    float ds[4];
#pragma unroll
    for (int rg = 0; rg < 4; ++rg) {
        int r = row0 + rbase4 + rg;
        ds[rg] = (r < N_NODES) ? dis[r] : 0.f;
    }

    __syncthreads();
#pragma unroll
    for (int nt = 0; nt < 8; ++nt) {
#pragma unroll
        for (int rg = 0; rg < 4; ++rg)
            sA[(rbase4 + rg) * 136 + nt * 16 + mrow] = f2h(acc[nt][rg] * ds[rg]);
    }
    __syncthreads();

#pragma unroll
    for (int k = 0; k < 4; ++k) {
        int idx = tid + k * 512;
        int m = idx >> 4, c16 = idx & 15;
        int r = row0 + m;
        if (r < N_NODES) {
            uint4 vv = *(const uint4*)&sA[m * 136 + c16 * 8];
            ((uint4*)out)[(size_t)r * 16 + c16] = vv;
        }
    }
}

// ---------------- CSR aggregation core (r5-proven gather pipeline) ----------------

struct Ictx { int n; int grp; int s0, s1, s2, s3, s4, s5; };
struct Gt { uint4 t0, t1, t2, t3, t4, t5, slf; };

__device__ __forceinline__ Ictx idx_stage(const int* __restrict__ esrc, int off, int n, int q) {
    Ictx c; c.n = n;
    const int* ep = esrc + off;
    int r0 = ep[q], r1 = ep[q + 4], r2 = ep[q + 8];
    int r3 = ep[q + 12], r4 = ep[q + 16], r5 = ep[q + 20];
    bool grp = (q + 12 < n);
    bool ok = (n <= q + 24);
    c.grp = grp;
    c.s0 = (grp || q < n)      ? r0 : ZROW;
    c.s1 = (grp || q + 4 < n)  ? r1 : ZROW;
    c.s2 = (grp || q + 8 < n)  ? r2 : ZROW;
    c.s3 = grp                 ? r3 : ZROW;
    c.s4 = (grp && ok && q + 16 < n) ? r4 : ZROW;
    c.s5 = (grp && ok && q + 20 < n) ? r5 : ZROW;
    return c;
}

__device__ __forceinline__ Gt gather_stage(const Ictx& c, int v, int l,
                                           const uint4* __restrict__ h16) {
    Gt g;
    g.t0 = h16[(size_t)c.s0 * 16 + l];
    g.t1 = h16[(size_t)c.s1 * 16 + l];
    g.t2 = h16[(size_t)c.s2 * 16 + l];
    g.t3 = h16[(size_t)c.s3 * 16 + l];
    g.t4 = h16[(size_t)c.s4 * 16 + l];
    g.t5 = h16[(size_t)c.s5 * 16 + l];
    g.slf = h16[(size_t)v * 16 + l];
    return g;
}

// gathers-accumulate + residual + quarter-butterfly + scale/relu/pack.
// Returns the fp16-packed row chunk (valid in all lanes; chunk index = l).
__device__ __forceinline__ uint4 acc_reduce(const Gt& g, const Ictx& c, int q, int l,
                                            const int* __restrict__ esrc, int off,
                                            const uint4* __restrict__ h16,
                                            float dsv, float4 b0, float4 b1) {
    uint4 aA = make_uint4(0, 0, 0, 0), aB = make_uint4(0, 0, 0, 0);
    aA = pk4(aA, g.t0);
    if (c.grp) aB = pk4(aB, g.t1); else aA = pk4(aA, g.t1);
    aA = pk4(aA, g.t2);
    if (c.grp) aB = pk4(aB, g.t3); else aA = pk4(aA, g.t3);
    aA = pk4(aA, g.t4);
    aA = pk4(aA, g.t5);
    if (c.n > q + 24) {
        const int* ep = esrc + off;
        int i = q + 16;
        for (; i + 12 < c.n; i += 16) {
            uint4 u0 = h16[(size_t)ep[i] * 16 + l];
            uint4 u1 = h16[(size_t)ep[i + 4] * 16 + l];
            uint4 u2 = h16[(size_t)ep[i + 8] * 16 + l];
            uint4 u3 = h16[(size_t)ep[i + 12] * 16 + l];
            aA = pk4(aA, u0); aB = pk4(aB, u1); aA = pk4(aA, u2); aB = pk4(aB, u3);
        }
        for (; i < c.n; i += 4) aA = pk4(aA, h16[(size_t)ep[i] * 16 + l]);
    }
    aA = pk4(aA, aB);
    aA.x = pkadd(aA.x, (uint)__shfl_xor((int)aA.x, 16));
    aA.y = pkadd(aA.y, (uint)__shfl_xor((int)aA.y, 16));
    aA.z = pkadd(aA.z, (uint)__shfl_xor((int)aA.z, 16));
    aA.w = pkadd(aA.w, (uint)__shfl_xor((int)aA.w, 16));
    aA.x = pkadd(aA.x, (uint)__shfl_xor((int)aA.x, 32));
    aA.y = pkadd(aA.y, (uint)__shfl_xor((int)aA.y, 32));
    aA.z = pkadd(aA.z, (uint)__shfl_xor((int)aA.z, 32));
    aA.w = pkadd(aA.w, (uint)__shfl_xor((int)aA.w, 32));

    aA = pk4(aA, g.slf);  // self-loop term
    float2 a0 = __half22float2(*(__half2*)&aA.x);
    float2 a1 = __half22float2(*(__half2*)&aA.y);
    float2 a2 = __half22float2(*(__half2*)&aA.z);
    float2 a3 = __half22float2(*(__half2*)&aA.w);
    a0.x = fmaxf(a0.x * dsv + b0.x, 0.f); a0.y = fmaxf(a0.y * dsv + b0.y, 0.f);
    a1.x = fmaxf(a1.x * dsv + b0.z, 0.f); a1.y = fmaxf(a1.y * dsv + b0.w, 0.f);
    a2.x = fmaxf(a2.x * dsv + b1.x, 0.f); a2.y = fmaxf(a2.y * dsv + b1.y, 0.f);
    a3.x = fmaxf(a3.x * dsv + b1.z, 0.f); a3.y = fmaxf(a3.y * dsv + b1.w, 0.f);
    __half2 o0 = __float22half2_rn(a0);
    __half2 o1 = __float22half2_rn(a1);
    __half2 o2 = __float22half2_rn(a2);
    __half2 o3 = __float22half2_rn(a3);
    return make_uint4(*(uint*)&o0, *(uint*)&o1, *(uint*)&o2, *(uint*)&o3);
}

// ---------------- layer1: agg + fused 128-wide GEMM -> x1, h2 ----------------
// After the 16 x1 rows are in the LDS tile, the block runs x1@W2 (B-fragments read
// straight from the swizzled W2s image in global: L1-resident) and writes h2.

__global__ __launch_bounds__(256) void k_agg_gemm(const int2* __restrict__ scnt,
                                                  const int* __restrict__ esrc,
                                                  const ushort* __restrict__ h,
                                                  const float* __restrict__ dis,
                                                  const float* __restrict__ bias,
                                                  const ushort* __restrict__ W2s,
                                                  ushort* __restrict__ x1,
                                                  ushort* __restrict__ h2) {
    __shared__ ushort tile[16 * 128];   // x1 rows, swizzled (MFMA A-operand)
    __shared__ ushort sBnc[16 * 136];   // h2 bounce
    const int t = threadIdx.x;
    const int w = t >> 6;
    const int vb0 = blockIdx.x * 16;
    const int vb = vb0 + w * 4;
    const int lane = t & 63, q = lane >> 4, l = lane & 15;
    const uint4* h16 = (const uint4*)h;

    int2 m0 = scnt[vb], m1 = scnt[vb + 1], m2 = scnt[vb + 2], m3 = scnt[vb + 3];
    float d0 = dis[vb], d1 = dis[vb + 1], d2 = dis[vb + 2], d3 = dis[vb + 3];
    float4 b0 = ((const float4*)bias)[2 * l];
    float4 b1 = ((const float4*)bias)[2 * l + 1];

    Ictx c0 = idx_stage(esrc, m0.x, m0.y, q);
    Gt g0 = gather_stage(c0, vb, l, h16);
    Ictx c1 = idx_stage(esrc, m1.x, m1.y, q);
    Gt g1 = gather_stage(c1, vb + 1, l, h16);
    Ictx c2 = idx_stage(esrc, m2.x, m2.y, q);
    uint4 ov = acc_reduce(g0, c0, q, l, esrc, m0.x, h16, d0, b0, b1);
    if (q == 0) {
        ((uint4*)x1)[(size_t)vb * 16 + l] = ov;
        *(uint4*)&tile[swz(w * 4 + 0, l * 8)] = ov;
    }
    Gt g2 = gather_stage(c2, vb + 2, l, h16);
    Ictx c3 = idx_stage(esrc, m3.x, m3.y, q);
    ov = acc_reduce(g1, c1, q, l, esrc, m1.x, h16, d1, b0, b1);
    if (q == 0) {
        ((uint4*)x1)[(size_t)(vb + 1) * 16 + l] = ov;
        *(uint4*)&tile[swz(w * 4 + 1, l * 8)] = ov;
    }
    Gt g3 = gather_stage(c3, vb + 3, l, h16);
    ov = acc_reduce(g2, c2, q, l, esrc, m2.x, h16, d2, b0, b1);
    if (q == 0) {
        ((uint4*)x1)[(size_t)(vb + 2) * 16 + l] = ov;
        *(uint4*)&tile[swz(w * 4 + 2, l * 8)] = ov;
    }
    ov = acc_reduce(g3, c3, q, l, esrc, m3.x, h16, d3, b0, b1);
    if (q == 0) {
        ((uint4*)x1)[(size_t)(vb + 3) * 16 + l] = ov;
        *(uint4*)&tile[swz(w * 4 + 3, l * 8)] = ov;
    }
    __syncthreads();

    // 16x128 @ 128x128: wave w owns out-col tiles 2w, 2w+1
    const int mrow = lane & 15, quad = lane >> 4;
    f32x4 acc0 = {}, acc1 = {};
    const int nt0 = 2 * w, nt1 = 2 * w + 1;
#pragma unroll
    for (int kc = 0; kc < 4; ++kc) {
        int g = kc * 4 + quad;
        half8 a = *(const half8*)&tile[mrow * 128 + ((g ^ mrow) << 3)];
        half8 bf0 = *(const half8*)&W2s[(nt0 * 16 + mrow) * 128 + ((g ^ mrow) << 3)];
        half8 bf1 = *(const half8*)&W2s[(nt1 * 16 + mrow) * 128 + ((g ^ mrow) << 3)];
        acc0 = __builtin_amdgcn_mfma_f32_16x16x32_f16(a, bf0, acc0, 0, 0, 0);
        acc1 = __builtin_amdgcn_mfma_f32_16x16x32_f16(a, bf1, acc1, 0, 0, 0);
    }
    float ds[4];
#pragma unroll
    for (int rg = 0; rg < 4; ++rg)
        ds[rg] = dis[vb0 + quad * 4 + rg];
#pragma unroll
    for (int rg = 0; rg < 4; ++rg) {
        sBnc[(quad * 4 + rg) * 136 + nt0 * 16 + mrow] = f2h(acc0[rg] * ds[rg]);
        sBnc[(quad * 4 + rg) * 136 + nt1 * 16 + mrow] = f2h(acc1[rg] * ds[rg]);
    }
    __syncthreads();

    int row = t >> 4, c16 = t & 15;   // 256 threads = 16 rows x 16 chunks
    uint4 vv = *(const uint4*)&sBnc[row * 136 + c16 * 8];
    ((uint4*)h2)[(size_t)(vb0 + row) * 16 + c16] = vv;
}

// ---------------- layer2: agg + fused 64-wide GEMM -> out (x2 never hits memory) --------

__global__ __launch_bounds__(256) void k_agg_out(const int2* __restrict__ scnt,
                                                 const int* __restrict__ esrc,
                                                 const ushort* __restrict__ h2,
                                                 const float* __restrict__ dis,
                                                 const float* __restrict__ bias,
                                                 const ushort* __restrict__ WoTs,
                                                 const float* __restrict__ bo,
                                                 const ushort* __restrict__ x1,
                                                 float* __restrict__ out) {
    __shared__ ushort tile[16 * 128];   // (x1+x2) rows, swizzled
    __shared__ float sOut[16 * 68];     // f32 out bounce
    const int t = threadIdx.x;
    const int w = t >> 6;
    const int vb0 = blockIdx.x * 16;
    const int vb = vb0 + w * 4;
    const int lane = t & 63, q = lane >> 4, l = lane & 15;
    const uint4* h16 = (const uint4*)h2;
    const uint4* x1q = (const uint4*)x1;

    int2 m0 = scnt[vb], m1 = scnt[vb + 1], m2 = scnt[vb + 2], m3 = scnt[vb + 3];
    float d0 = dis[vb], d1 = dis[vb + 1], d2 = dis[vb + 2], d3 = dis[vb + 3];
    float4 b0 = ((const float4*)bias)[2 * l];
    float4 b1 = ((const float4*)bias)[2 * l + 1];

    Ictx c0 = idx_stage(esrc, m0.x, m0.y, q);
    Gt g0 = gather_stage(c0, vb, l, h16);
    uint4 xr0 = x1q[(size_t)vb * 16 + l];
    Ictx c1 = idx_stage(esrc, m1.x, m1.y, q);
    Gt g1 = gather_stage(c1, vb + 1, l, h16);
    uint4 xr1 = x1q[(size_t)(vb + 1) * 16 + l];
    Ictx c2 = idx_stage(esrc, m2.x, m2.y, q);
    uint4 ov = acc_reduce(g0, c0, q, l, esrc, m0.x, h16, d0, b0, b1);
    if (q == 0) *(uint4*)&tile[swz(w * 4 + 0, l * 8)] = pk4(ov, xr0);  // x1+x2 (hadd2)
    Gt g2 = gather_stage(c2, vb + 2, l, h16);
    uint4 xr2 = x1q[(size_t)(vb + 2) * 16 + l];
    Ictx c3 = idx_stage(esrc, m3.x, m3.y, q);
    uint4 xr3 = x1q[(size_t)(vb + 3) * 16 + l];
    ov = acc_reduce(g1, c1, q, l, esrc, m1.x, h16, d1, b0, b1);
    if (q == 0) *(uint4*)&tile[swz(w * 4 + 1, l * 8)] = pk4(ov, xr1);
    Gt g3 = gather_stage(c3, vb + 3, l, h16);
    ov = acc_reduce(g2, c2, q, l, esrc, m2.x, h16, d2, b0, b1);
    if (q == 0) *(uint4*)&tile[swz(w * 4 + 2, l * 8)] = pk4(ov, xr2);
    ov = acc_reduce(g3, c3, q, l, esrc, m3.x, h16, d3, b0, b1);
    if (q == 0) *(uint4*)&tile[swz(w * 4 + 3, l * 8)] = pk4(ov, xr3);
    __syncthreads();

    // 16x128 @ 128x64: wave w owns out-col tile w
    const int mrow = lane & 15, quad = lane >> 4;
    f32x4 acc = {};
#pragma unroll
    for (int kc = 0; kc < 4; ++kc) {
        int g = kc * 4 + quad;
        half8 a = *(const half8*)&tile[mrow * 128 + ((g ^ mrow) << 3)];
        half8 bf = *(const half8*)&WoTs[(w * 16 + mrow) * 128 + ((g ^ mrow) << 3)];
        acc = __builtin_amdgcn_mfma_f32_16x16x32_f16(a, bf, acc, 0, 0, 0);
    }
    float bb = bo[w * 16 + mrow];
#pragma unroll
    for (int rg = 0; rg < 4; ++rg)
        sOut[(quad * 4 + rg) * 68 + w * 16 + mrow] = acc[rg] + bb;
    __syncthreads();

    int row = t >> 4, c16 = t & 15;   // 256 threads = 16 rows x 16 f32x4-chunks
    uint4 vv = *(const uint4*)&sOut[row * 68 + c16 * 4];
    ((uint4*)out)[(size_t)(vb0 + row) * 16 + c16] = vv;
}

// ---------------- launch ----------------

extern "C" void kernel_launch(void* const* d_in, const int* in_sizes, int n_in,
                              void* d_out, int out_size, void* d_ws, size_t ws_size,
                              hipStream_t stream) {
    const float* x  = (const float*)d_in[0];
    const int*   ei = (const int*)d_in[1];
    const int*   src = ei;
    const int*   dst = ei + N_EDGES;
    const float* W1 = (const float*)d_in[2];
    const float* b1 = (const float*)d_in[3];
    const float* W2 = (const float*)d_in[4];
    const float* b2 = (const float*)d_in[5];
    const float* Wo = (const float*)d_in[6];
    const float* bo = (const float*)d_in[7];
    float* out = (float*)d_out;

    char* ws = (char*)d_ws;
    int*    bfill  = (int*)ws;            ws += 2048;
    int2*   scnt   = (int2*)ws;           ws += 800000;                    // packed (start,cnt)
    float*  dis    = (float*)ws;          ws += 400000;
    int*    bin    = (int*)ws;            ws += (size_t)NBUCKET * CAP * 4; // 12.8 MB
    int*    esrc   = (int*)ws;            ws += (size_t)N_EDGES * 4;
    ushort* W1s    = (ushort*)ws;         ws += 32768;
    ushort* W2s    = (ushort*)ws;         ws += 32768;
    ushort* WoTs   = (ushort*)ws;         ws += 16384;
    ushort* h      = (ushort*)ws;         ws += (size_t)(N_NODES + 1) * CH * 2;  // +zero row
    ushort* x1     = (ushort*)ws;         ws += (size_t)N_NODES * CH * 2;
    ushort* h2     = (ushort*)ws;         // (N_NODES+1)*CH f16, +zero row

    const int gA = N_NODES / 16;           // 6250 (4 waves x 4 nodes per block)

    // CSR build: memset -> fused bin+prep (+zero rows) -> build (self-scan)
    hipMemsetAsync(bfill, 0, 2048, stream);
    k_bin_prep<<<NBUCKET + 81, 512, 0, stream>>>(src, dst, bfill, bin,
                                                 W1, W2, Wo, W1s, W2s, WoTs, h, h2);
    k_build<<<NBUCKET, 512, 0, stream>>>(bfill, bin, esrc, scnt, dis);

    // layer 1 GEMM
    k_gemm_mfma<<<GG, 512, 0, stream>>>(x, W1s, dis, h);

    // layer 1 agg + fused layer-2 GEMM (x1, h2)
    k_agg_gemm<<<gA, 256, 0, stream>>>(scnt, esrc, h, dis, b1, W2s, x1, h2);

    // layer 2 agg + fused output projection (x2 stays in registers)
    k_agg_out<<<gA, 256, 0, stream>>>(scnt, esrc, h2, dis, b2, WoTs, bo, x1, out);
}